// Round 17
// baseline (150.901 us; speedup 1.0000x reference)
//
#include <hip/hip_runtime.h>
#include <hip/hip_bf16.h>

#define VOCAB  200000
#define NTILES 12800            // 204800 rows / 16
#define GRID   512              // persistent blocks; 2 resident/CU
#define ITERS  25               // NTILES / GRID
#define DEPTH  3                // LDS A-buffer ring (2 tiles prefetch ahead)

typedef __attribute__((ext_vector_type(4))) float  f32x4;
typedef __attribute__((ext_vector_type(4))) int    i32x4;
typedef __attribute__((ext_vector_type(8))) __bf16 bf16x8;

typedef const __attribute__((address_space(1))) unsigned int* gas_u32p;
typedef __attribute__((address_space(3))) unsigned int* las_u32p;

__device__ __forceinline__ __bf16 f2bf(float f) {
    unsigned u = __builtin_bit_cast(unsigned, f);
    u += 0x7FFFu + ((u >> 16) & 1u);           // round-to-nearest-even
    unsigned short s = (unsigned short)(u >> 16);
    return __builtin_bit_cast(__bf16, s);
}

// Pack B into MFMA fragment order (verified round 1).
// k = a*16 + b;  B[k][j] = core1[b, j, a], core1 is (16,256,16).
// bpk[(kk*16 + nt)*64 + lane] : lane l elem e = B[kk*32 + (l>>4)*8 + e][nt*16 + (l&15)]
__global__ void pack_b_kernel(const float* __restrict__ core1, bf16x8* __restrict__ bpk) {
    int t    = blockIdx.x * 256 + threadIdx.x;   // 0..8191
    int lane = t & 63;
    int nt   = (t >> 6) & 15;
    int kk   = t >> 10;
    int j     = nt * 16 + (lane & 15);
    int kbase = kk * 32 + ((lane >> 4) * 8);
    bf16x8 v;
#pragma unroll
    for (int e = 0; e < 8; ++e) {
        int k = kbase + e;
        int b = k & 15, a = k >> 4;
        v[e] = f2bf(core1[(b * 256 + j) * 16 + a]);
    }
    bpk[t] = v;
}

// Repack A: core0 (16, VOCAB, 16) f32 -> wbf[v][k] bf16 (512 B/row), k=a*16+b.
// Thread t: v = t>>3, j = t&7 handles k = j*32..j*32+31 (a = 2j, 2j+1; all b).
// Reads 2x 64 B contiguous (consecutive-v lanes contiguous); writes 64 B at
// v*512 + j*64 -> consecutive threads write contiguous bytes. RNE via cvt_pk
// (same rounding the r16 kernel applied in-register -> numerically identical).
__global__ __launch_bounds__(256) void repack_a_kernel(const float* __restrict__ core0,
                                                       char* __restrict__ wbf) {
    int t = blockIdx.x * 256 + threadIdx.x;     // 0 .. VOCAB*8-1
    int v = t >> 3, j = t & 7;
    const float* s0 = core0 + ((long)(2 * j)     * VOCAB + v) * 16;
    const float* s1 = core0 + ((long)(2 * j + 1) * VOCAB + v) * 16;
    f32x4 a0 = *(const f32x4*)(s0),     a1 = *(const f32x4*)(s0 + 4);
    f32x4 a2 = *(const f32x4*)(s0 + 8), a3 = *(const f32x4*)(s0 + 12);
    f32x4 b0 = *(const f32x4*)(s1),     b1 = *(const f32x4*)(s1 + 4);
    f32x4 b2 = *(const f32x4*)(s1 + 8), b3 = *(const f32x4*)(s1 + 12);
    int p[16];
    asm("v_cvt_pk_bf16_f32 %0, %1, %2" : "=v"(p[0])  : "v"(a0[0]), "v"(a0[1]));
    asm("v_cvt_pk_bf16_f32 %0, %1, %2" : "=v"(p[1])  : "v"(a0[2]), "v"(a0[3]));
    asm("v_cvt_pk_bf16_f32 %0, %1, %2" : "=v"(p[2])  : "v"(a1[0]), "v"(a1[1]));
    asm("v_cvt_pk_bf16_f32 %0, %1, %2" : "=v"(p[3])  : "v"(a1[2]), "v"(a1[3]));
    asm("v_cvt_pk_bf16_f32 %0, %1, %2" : "=v"(p[4])  : "v"(a2[0]), "v"(a2[1]));
    asm("v_cvt_pk_bf16_f32 %0, %1, %2" : "=v"(p[5])  : "v"(a2[2]), "v"(a2[3]));
    asm("v_cvt_pk_bf16_f32 %0, %1, %2" : "=v"(p[6])  : "v"(a3[0]), "v"(a3[1]));
    asm("v_cvt_pk_bf16_f32 %0, %1, %2" : "=v"(p[7])  : "v"(a3[2]), "v"(a3[3]));
    asm("v_cvt_pk_bf16_f32 %0, %1, %2" : "=v"(p[8])  : "v"(b0[0]), "v"(b0[1]));
    asm("v_cvt_pk_bf16_f32 %0, %1, %2" : "=v"(p[9])  : "v"(b0[2]), "v"(b0[3]));
    asm("v_cvt_pk_bf16_f32 %0, %1, %2" : "=v"(p[10]) : "v"(b1[0]), "v"(b1[1]));
    asm("v_cvt_pk_bf16_f32 %0, %1, %2" : "=v"(p[11]) : "v"(b1[2]), "v"(b1[3]));
    asm("v_cvt_pk_bf16_f32 %0, %1, %2" : "=v"(p[12]) : "v"(b2[0]), "v"(b2[1]));
    asm("v_cvt_pk_bf16_f32 %0, %1, %2" : "=v"(p[13]) : "v"(b2[2]), "v"(b2[3]));
    asm("v_cvt_pk_bf16_f32 %0, %1, %2" : "=v"(p[14]) : "v"(b3[0]), "v"(b3[1]));
    asm("v_cvt_pk_bf16_f32 %0, %1, %2" : "=v"(p[15]) : "v"(b3[2]), "v"(b3[3]));
    char* dst = wbf + (long)v * 512 + j * 64;
    i32x4 o0 = { p[0], p[1], p[2], p[3] };      // k = j*32 .. +15 (a=2j)
    i32x4 o1 = { p[4], p[5], p[6], p[7] };
    i32x4 o2 = { p[8], p[9], p[10], p[11] };    // k = j*32+16 .. +31 (a=2j+1)
    i32x4 o3 = { p[12], p[13], p[14], p[15] };
    *(i32x4*)(dst)      = o0;  *(i32x4*)(dst + 16) = o1;
    *(i32x4*)(dst + 32) = o2;  *(i32x4*)(dst + 48) = o3;
}

// bf16 A-gather: ONE inst/wave/tile. Wave w = slab kk=w; lane l=(q,r) fetches
// 16 B at wbf[idx_r]*512 + w*64 + q*16 (= k = w*32+q*8..+8 of row idx_r; the
// exact A-fragment, r9-verified mapping). Per row: 512 B contiguous (8-line
// DRAM burst vs 16 scattered lines from fp32 core0). LDS: abuf + w*1024 +
// lane*16 -> compute af = ds_read_b128 at cur + kk*1024 + lane*16, no cvt.
__device__ __forceinline__ void issue_gather_bf(const char* __restrict__ wbf, int idx,
                                                int wave, int q, char* abuf) {
    const char* src = wbf + (long)idx * 512 + wave * 64 + q * 16;
    __builtin_amdgcn_global_load_lds((gas_u32p)src, (las_u32p)(abuf + wave * 1024), 16, 0, 0);
}

// r16-proven skeleton, bf16-table gather. Per iter per wave: 1 gather + 8 f32
// C-stores. vmcnt(16): ops newer than g(i+1) at the wait = st(i-1)[8] +
// g(i+2)[1] + st(i)[8] = 17 steady / 16 tail -> vmcnt(16) retires g(i+1) in
// both regimes (if g(i+1) outstanding, count >= 17 > 16). Barrier publishes.
__global__ __launch_bounds__(512, 4) void tr_embed_bf_kernel(
        const int* __restrict__ x, const char* __restrict__ wbf,
        const bf16x8* __restrict__ bpk, float* __restrict__ out) {
    __shared__ char lds[DEPTH * 8192 + ITERS * 16 * 4];    // A-ring (8 KB/tile) | idx
    char* const ldsA = lds;
    int*  const sIdx = (int*)(lds + DEPTH * 8192);
    const int tid  = threadIdx.x;
    const int lane = tid & 63;
    const int wave = tid >> 6;                  // 0..7
    const int r    = lane & 15;
    const int q    = lane >> 4;

    // B panel -> registers: wave w owns nt = 2w, 2w+1 (proven r9)
    bf16x8 B0[8], B1[8];
#pragma unroll
    for (int kk = 0; kk < 8; ++kk) {
        B0[kk] = bpk[(kk * 16 + 2 * wave)     * 64 + lane];
        B1[kk] = bpk[(kk * 16 + 2 * wave + 1) * 64 + lane];
    }

    const int b0 = blockIdx.x;

    // stage all idx values into LDS (off the vmcnt path; proven r9)
    for (int j = tid; j < ITERS * 16; j += 512)
        sIdx[j] = x[(b0 + (j >> 4) * GRID) * 16 + (j & 15)];
    __syncthreads();

    // prologue: gather tiles 0,1 into ring slots 0,1; full drain
#pragma unroll
    for (int p = 0; p < 2; ++p)
        issue_gather_bf(wbf, sIdx[p * 16 + r], wave, q, ldsA + p * 8192);
    asm volatile("s_waitcnt vmcnt(0)" ::: "memory");
    __builtin_amdgcn_s_barrier();
    __builtin_amdgcn_sched_barrier(0);

    int slot = 0;
    for (int i = 0; i < ITERS; ++i) {
        const int t = b0 + i * GRID;
        char* cur = ldsA + slot * 8192;

        // issue gather for tile i+2 into ring slot (slot+2)%3
        if (i + 2 < ITERS) {
            int ns = slot + 2; if (ns >= DEPTH) ns -= DEPTH;
            issue_gather_bf(wbf, sIdx[(i + 2) * 16 + r], wave, q, ldsA + ns * 8192);
        }
        __builtin_amdgcn_sched_barrier(0);      // pin gather issue at iter top

        // ---- compute 16 rows x 32 cols per wave (bf16 LDS A + reg B) ----
        f32x4 acc0 = {}, acc1 = {};
#pragma unroll
        for (int kk = 0; kk < 8; ++kk) {
            bf16x8 af = *(const bf16x8*)(cur + kk * 1024 + lane * 16);
            acc0 = __builtin_amdgcn_mfma_f32_16x16x32_bf16(af, B0[kk], acc0, 0, 0, 0);
            acc1 = __builtin_amdgcn_mfma_f32_16x16x32_bf16(af, B1[kk], acc1, 0, 0, 0);
        }

        // ---- direct C stores (proven r9): col = lane&15, row = q*4 + e ----
        float* ob = out + (long)t * 16 * 256 + (q * 4) * 256 + 2 * wave * 16 + r;
#pragma unroll
        for (int e = 0; e < 4; ++e) {
            ob[e * 256]      = acc0[e];
            ob[e * 256 + 16] = acc1[e];
        }

        asm volatile("s_waitcnt vmcnt(16)" ::: "memory");
        __builtin_amdgcn_s_barrier();
        __builtin_amdgcn_sched_barrier(0);

        slot = (slot == DEPTH - 1) ? 0 : slot + 1;
    }
}

// ---------------- fallback: r16 kernel (proven, 108 µs) for small ws ----------------
__device__ __forceinline__ void issue_gather(const float* __restrict__ core0, int idx,
                                             int kk, char* abuf, int lane) {
    const int q = lane >> 4;
#pragma unroll
    for (int h = 0; h < 2; ++h) {
        const float* src = core0 + ((long)(2 * kk + h) * VOCAB + idx) * 16 + q * 4;
        __builtin_amdgcn_global_load_lds((gas_u32p)src,
                                         (las_u32p)(abuf + kk * 2048 + h * 1024), 16, 0, 0);
    }
}

__global__ __launch_bounds__(512, 4) void tr_embed_kernel(
        const int* __restrict__ x, const float* __restrict__ core0,
        const bf16x8* __restrict__ bpk, float* __restrict__ out) {
    __shared__ char lds[DEPTH * 16384 + ITERS * 16 * 4];
    char* const ldsA = lds;
    int*  const sIdx = (int*)(lds + DEPTH * 16384);
    const int tid  = threadIdx.x;
    const int lane = tid & 63;
    const int wave = tid >> 6;
    const int r    = lane & 15;
    const int q    = lane >> 4;
    const int laneOff = q * 512 + r * 16;

    bf16x8 B0[8], B1[8];
#pragma unroll
    for (int kk = 0; kk < 8; ++kk) {
        B0[kk] = bpk[(kk * 16 + 2 * wave)     * 64 + lane];
        B1[kk] = bpk[(kk * 16 + 2 * wave + 1) * 64 + lane];
    }

    const int b0 = blockIdx.x;
    for (int j = tid; j < ITERS * 16; j += 512)
        sIdx[j] = x[(b0 + (j >> 4) * GRID) * 16 + (j & 15)];
    __syncthreads();

#pragma unroll
    for (int p = 0; p < 2; ++p)
        issue_gather(core0, sIdx[p * 16 + r], wave, ldsA + p * 16384, lane);
    asm volatile("s_waitcnt vmcnt(0)" ::: "memory");
    __builtin_amdgcn_s_barrier();
    __builtin_amdgcn_sched_barrier(0);

    int slot = 0;
    for (int i = 0; i < ITERS; ++i) {
        const int t = b0 + i * GRID;
        char* cur = ldsA + slot * 16384;
        if (i + 2 < ITERS) {
            int ns = slot + 2; if (ns >= DEPTH) ns -= DEPTH;
            issue_gather(core0, sIdx[(i + 2) * 16 + r], wave, ldsA + ns * 16384, lane);
        }
        __builtin_amdgcn_sched_barrier(0);

        f32x4 acc0 = {}, acc1 = {};
#pragma unroll
        for (int kk = 0; kk < 8; ++kk) {
            f32x4 lo = *(const f32x4*)(cur + kk * 2048 + laneOff);
            f32x4 hi = *(const f32x4*)(cur + kk * 2048 + laneOff + 256);
            int p0, p1, p2, p3;
            asm("v_cvt_pk_bf16_f32 %0, %1, %2" : "=v"(p0) : "v"(lo[0]), "v"(lo[1]));
            asm("v_cvt_pk_bf16_f32 %0, %1, %2" : "=v"(p1) : "v"(lo[2]), "v"(lo[3]));
            asm("v_cvt_pk_bf16_f32 %0, %1, %2" : "=v"(p2) : "v"(hi[0]), "v"(hi[1]));
            asm("v_cvt_pk_bf16_f32 %0, %1, %2" : "=v"(p3) : "v"(hi[2]), "v"(hi[3]));
            i32x4 pk = { p0, p1, p2, p3 };
            bf16x8 af = __builtin_bit_cast(bf16x8, pk);
            acc0 = __builtin_amdgcn_mfma_f32_16x16x32_bf16(af, B0[kk], acc0, 0, 0, 0);
            acc1 = __builtin_amdgcn_mfma_f32_16x16x32_bf16(af, B1[kk], acc1, 0, 0, 0);
        }

        float* ob = out + (long)t * 16 * 256 + (q * 4) * 256 + 2 * wave * 16 + r;
#pragma unroll
        for (int e = 0; e < 4; ++e) {
            ob[e * 256]      = acc0[e];
            ob[e * 256 + 16] = acc1[e];
        }
        asm volatile("s_waitcnt vmcnt(16)" ::: "memory");
        __builtin_amdgcn_s_barrier();
        __builtin_amdgcn_sched_barrier(0);
        slot = (slot == DEPTH - 1) ? 0 : slot + 1;
    }
}

extern "C" void kernel_launch(void* const* d_in, const int* in_sizes, int n_in,
                              void* d_out, int out_size, void* d_ws, size_t ws_size,
                              hipStream_t stream) {
    const int*   x     = (const int*)d_in[0];
    const float* core0 = (const float*)d_in[1];
    const float* core1 = (const float*)d_in[2];
    float* out = (float*)d_out;
    bf16x8* bpk = (bf16x8*)d_ws;                          // 128 KB
    char*   wbf = (char*)d_ws + 131072;                   // 102.4 MB bf16 table

    const size_t WS_NEED = 131072 + (size_t)VOCAB * 512;  // 102,531,072 B

    pack_b_kernel<<<32, 256, 0, stream>>>(core1, bpk);
    if (ws_size >= WS_NEED) {
        repack_a_kernel<<<VOCAB * 8 / 256, 256, 0, stream>>>(core0, wbf);
        tr_embed_bf_kernel<<<GRID, 512, 0, stream>>>(x, wbf, bpk, out);
    } else {
        tr_embed_kernel<<<GRID, 512, 0, stream>>>(x, core0, bpk, out);
    }
}

// Round 18
// 131.470 us; speedup vs baseline: 1.1478x; 1.1478x over previous
//
#include <hip/hip_runtime.h>
#include <hip/hip_bf16.h>

#define VOCAB  200000
#define NROWS  204800
#define NTILES 12800            // NROWS / 16
#define GRID   512              // main-kernel blocks; 2 resident/CU
#define ITERS  25               // NTILES / GRID (contiguous: tile = b0*25+i)
#define DEPTH  3                // LDS A-buffer ring
#define NBUCK  12500            // sort buckets: idx >> 4

typedef __attribute__((ext_vector_type(4))) float  f32x4;
typedef __attribute__((ext_vector_type(4))) int    i32x4;
typedef __attribute__((ext_vector_type(8))) __bf16 bf16x8;

typedef const __attribute__((address_space(1))) unsigned int* gas_u32p;
typedef __attribute__((address_space(3))) unsigned int* las_u32p;

__device__ __forceinline__ __bf16 f2bf(float f) {
    unsigned u = __builtin_bit_cast(unsigned, f);
    u += 0x7FFFu + ((u >> 16) & 1u);           // round-to-nearest-even
    unsigned short s = (unsigned short)(u >> 16);
    return __builtin_bit_cast(__bf16, s);
}

// Pack B into MFMA fragment order (verified round 1).
__global__ void pack_b_kernel(const float* __restrict__ core1, bf16x8* __restrict__ bpk) {
    int t    = blockIdx.x * 256 + threadIdx.x;   // 0..8191
    int lane = t & 63;
    int nt   = (t >> 6) & 15;
    int kk   = t >> 10;
    int j     = nt * 16 + (lane & 15);
    int kbase = kk * 32 + ((lane >> 4) * 8);
    bf16x8 v;
#pragma unroll
    for (int e = 0; e < 8; ++e) {
        int k = kbase + e;
        int b = k & 15, a = k >> 4;
        v[e] = f2bf(core1[(b * 256 + j) * 16 + a]);
    }
    bpk[t] = v;
}

// ---- deterministic-output counting sort of row-slots by idx ----
__global__ void zero_hist_kernel(int* __restrict__ hist) {
    int t = blockIdx.x * 1024 + threadIdx.x;
    if (t < 13312) hist[t] = 0;
}

__global__ void hist_kernel(const int* __restrict__ x, int* __restrict__ hist) {
    int i = blockIdx.x * 1024 + threadIdx.x;    // 0..204799
    atomicAdd(&hist[x[i] >> 4], 1);
}

// One block, 1024 threads: exclusive prefix-sum of 12500 bucket counts into basec.
__global__ __launch_bounds__(1024) void scan_kernel(const int* __restrict__ hist,
                                                    int* __restrict__ basec) {
    __shared__ int ps[1024];
    const int tt = threadIdx.x;
    const int c0 = tt * 13;
    int part = 0;
#pragma unroll
    for (int k = 0; k < 13; ++k) { int b = c0 + k; if (b < NBUCK) part += hist[b]; }
    ps[tt] = part; __syncthreads();
    for (int off = 1; off < 1024; off <<= 1) {
        int v = (tt >= off) ? ps[tt - off] : 0; __syncthreads();
        ps[tt] += v; __syncthreads();
    }
    int run = ps[tt] - part;                    // exclusive base of this chunk
#pragma unroll
    for (int k = 0; k < 13; ++k) {
        int b = c0 + k;
        if (b < NBUCK) { basec[b] = run; run += hist[b]; }
    }
}

// Scatter: perm[pos] = row-slot i, pos deterministic up to within-bucket order
// (output values are order-independent: each out row depends only on its idx).
__global__ void scatter_kernel(const int* __restrict__ x, int* __restrict__ basec,
                               int* __restrict__ perm) {
    int i = blockIdx.x * 1024 + threadIdx.x;    // 0..204799
    int pos = atomicAdd(&basec[x[i] >> 4], 1);
    perm[pos] = i;
}

// A-gather, full-line coalesced (proven r16). Inst (kk,h): lane (q,r) fetches
// core0[plane 2kk+h][idx_r][q*4..q*4+3] -> 4 q-lanes read one 64 B line/row.
// LDS image: abuf + kk*2048 + h*1024 + lane*16; fragment laneOff = q*512+r*16.
__device__ __forceinline__ void issue_gather(const float* __restrict__ core0, int idx,
                                             int kk, char* abuf, int lane) {
    const int q = lane >> 4;
#pragma unroll
    for (int h = 0; h < 2; ++h) {
        const float* src = core0 + ((long)(2 * kk + h) * VOCAB + idx) * 16 + q * 4;
        __builtin_amdgcn_global_load_lds((gas_u32p)src,
                                         (las_u32p)(abuf + kk * 2048 + h * 1024), 16, 0, 0);
    }
}

// Sorted main kernel: r16 gather/compute + r13 C-LDS funnel, tiles processed in
// idx-sorted order (block b owns sorted slots [400b,400b+400) = 25 tiles).
// Reads sweep core0 in ascending row order (dups adjacent -> cache hits);
// writes go to permuted rows as 1 KB contiguous bursts via the funnel.
// vmcnt(4): queue newest->oldest at the wait is st(i)[2], g(i+2)[2], st(i-1)[2],
// g(i+1)[2],...; vmcnt(4) leaves only st(i)+g(i+2) outstanding -> g(i+1)
// retired in steady AND tail regimes (tail: st(i)2+st(i-1)2 newest, same bound).
__global__ __launch_bounds__(512, 4) void tr_embed_sorted_kernel(
        const int* __restrict__ x, const float* __restrict__ core0,
        const bf16x8* __restrict__ bpk, const int* __restrict__ perm,
        float* __restrict__ out) {
    __shared__ char lds[DEPTH * 16384 + 16384 + 400 * 4 + 400 * 4];
    char* const ldsA = lds;
    char* const ldsC = lds + DEPTH * 16384;
    int*  const sIdx  = (int*)(lds + DEPTH * 16384 + 16384);
    int*  const sPerm = sIdx + 400;
    const int tid  = threadIdx.x;
    const int lane = tid & 63;
    const int wave = tid >> 6;                  // 0..7
    const int r    = lane & 15;
    const int q    = lane >> 4;
    const int laneOff = q * 512 + r * 16;

    // B panel -> registers (proven r9)
    bf16x8 B0[8], B1[8];
#pragma unroll
    for (int kk = 0; kk < 8; ++kk) {
        B0[kk] = bpk[(kk * 16 + 2 * wave)     * 64 + lane];
        B1[kk] = bpk[(kk * 16 + 2 * wave + 1) * 64 + lane];
    }

    const int b0 = blockIdx.x;

    // stage this block's 400 sorted slots: perm (sequential) + x[perm] (4B gather)
    for (int j = tid; j < 400; j += 512) {
        int p = perm[b0 * 400 + j];
        sPerm[j] = p;
        sIdx[j]  = x[p];
    }
    __syncthreads();

    // prologue: gather tiles 0,1
#pragma unroll
    for (int p = 0; p < 2; ++p)
        issue_gather(core0, sIdx[p * 16 + r], wave, ldsA + p * 16384, lane);
    asm volatile("s_waitcnt vmcnt(0)" ::: "memory");
    __builtin_amdgcn_s_barrier();
    __builtin_amdgcn_sched_barrier(0);

    int slot = 0;
    for (int i = 0; i < ITERS; ++i) {
        char* cur = ldsA + slot * 16384;

        if (i + 2 < ITERS) {
            int ns = slot + 2; if (ns >= DEPTH) ns -= DEPTH;
            issue_gather(core0, sIdx[(i + 2) * 16 + r], wave, ldsA + ns * 16384, lane);
        }
        __builtin_amdgcn_sched_barrier(0);      // pin gather issue at iter top

        // ---- compute (proven r16): 16 rows x 32 cols per wave ----
        f32x4 acc0 = {}, acc1 = {};
#pragma unroll
        for (int kk = 0; kk < 8; ++kk) {
            f32x4 lo = *(const f32x4*)(cur + kk * 2048 + laneOff);
            f32x4 hi = *(const f32x4*)(cur + kk * 2048 + laneOff + 256);
            int p0, p1, p2, p3;                 // RNE packed f32->bf16
            asm("v_cvt_pk_bf16_f32 %0, %1, %2" : "=v"(p0) : "v"(lo[0]), "v"(lo[1]));
            asm("v_cvt_pk_bf16_f32 %0, %1, %2" : "=v"(p1) : "v"(lo[2]), "v"(lo[3]));
            asm("v_cvt_pk_bf16_f32 %0, %1, %2" : "=v"(p2) : "v"(hi[0]), "v"(hi[1]));
            asm("v_cvt_pk_bf16_f32 %0, %1, %2" : "=v"(p3) : "v"(hi[2]), "v"(hi[3]));
            i32x4 pk = { p0, p1, p2, p3 };
            bf16x8 af = __builtin_bit_cast(bf16x8, pk);
            acc0 = __builtin_amdgcn_mfma_f32_16x16x32_bf16(af, B0[kk], acc0, 0, 0, 0);
            acc1 = __builtin_amdgcn_mfma_f32_16x16x32_bf16(af, B1[kk], acc1, 0, 0, 0);
        }

        // ---- C -> swizzled LDS tile (proven r13) ----
#pragma unroll
        for (int e = 0; e < 4; ++e) {
            int row = q * 4 + e;
            int xr  = (row & 7) << 2;
            *(float*)(ldsC + row * 1024 + (((2 * wave * 16 + r)      ^ xr) << 2)) = acc0[e];
            *(float*)(ldsC + row * 1024 + (((2 * wave * 16 + 16 + r) ^ xr) << 2)) = acc1[e];
        }
        asm volatile("s_waitcnt lgkmcnt(0)" ::: "memory");
        __builtin_amdgcn_sched_barrier(0);
        __builtin_amdgcn_s_barrier();           // C tile visible
        __builtin_amdgcn_sched_barrier(0);

        // ---- store rows 2w, 2w+1 to their PERMUTED output rows (1 KB each) ----
        {
            int r0w = 2 * wave, r1w = 2 * wave + 1;
            int row0 = sPerm[i * 16 + r0w];
            int row1 = sPerm[i * 16 + r1w];
            f32x4 v0 = *(const f32x4*)(ldsC + r0w * 1024 + (((lane * 4) ^ ((r0w & 7) << 2)) << 2));
            f32x4 v1 = *(const f32x4*)(ldsC + r1w * 1024 + (((lane * 4) ^ ((r1w & 7) << 2)) << 2));
            *((f32x4*)(out + (long)row0 * 256) + lane) = v0;
            *((f32x4*)(out + (long)row1 * 256) + lane) = v1;
        }

        asm volatile("s_waitcnt vmcnt(4)" ::: "memory");
        __builtin_amdgcn_s_barrier();
        __builtin_amdgcn_sched_barrier(0);

        slot = (slot == DEPTH - 1) ? 0 : slot + 1;
    }
}

// ---------------- fallback: r16 kernel (proven, 108 µs) for small ws ----------------
__global__ __launch_bounds__(512, 4) void tr_embed_kernel(
        const int* __restrict__ x, const float* __restrict__ core0,
        const bf16x8* __restrict__ bpk, float* __restrict__ out) {
    __shared__ char lds[DEPTH * 16384 + ITERS * 16 * 4];
    char* const ldsA = lds;
    int*  const sIdx = (int*)(lds + DEPTH * 16384);
    const int tid  = threadIdx.x;
    const int lane = tid & 63;
    const int wave = tid >> 6;
    const int r    = lane & 15;
    const int q    = lane >> 4;
    const int laneOff = q * 512 + r * 16;

    bf16x8 B0[8], B1[8];
#pragma unroll
    for (int kk = 0; kk < 8; ++kk) {
        B0[kk] = bpk[(kk * 16 + 2 * wave)     * 64 + lane];
        B1[kk] = bpk[(kk * 16 + 2 * wave + 1) * 64 + lane];
    }

    const int b0 = blockIdx.x;
    for (int j = tid; j < ITERS * 16; j += 512)
        sIdx[j] = x[(b0 + (j >> 4) * GRID) * 16 + (j & 15)];
    __syncthreads();

#pragma unroll
    for (int p = 0; p < 2; ++p)
        issue_gather(core0, sIdx[p * 16 + r], wave, ldsA + p * 16384, lane);
    asm volatile("s_waitcnt vmcnt(0)" ::: "memory");
    __builtin_amdgcn_s_barrier();
    __builtin_amdgcn_sched_barrier(0);

    int slot = 0;
    for (int i = 0; i < ITERS; ++i) {
        const int t = b0 + i * GRID;
        char* cur = ldsA + slot * 16384;
        if (i + 2 < ITERS) {
            int ns = slot + 2; if (ns >= DEPTH) ns -= DEPTH;
            issue_gather(core0, sIdx[(i + 2) * 16 + r], wave, ldsA + ns * 16384, lane);
        }
        __builtin_amdgcn_sched_barrier(0);

        f32x4 acc0 = {}, acc1 = {};
#pragma unroll
        for (int kk = 0; kk < 8; ++kk) {
            f32x4 lo = *(const f32x4*)(cur + kk * 2048 + laneOff);
            f32x4 hi = *(const f32x4*)(cur + kk * 2048 + laneOff + 256);
            int p0, p1, p2, p3;
            asm("v_cvt_pk_bf16_f32 %0, %1, %2" : "=v"(p0) : "v"(lo[0]), "v"(lo[1]));
            asm("v_cvt_pk_bf16_f32 %0, %1, %2" : "=v"(p1) : "v"(lo[2]), "v"(lo[3]));
            asm("v_cvt_pk_bf16_f32 %0, %1, %2" : "=v"(p2) : "v"(hi[0]), "v"(hi[1]));
            asm("v_cvt_pk_bf16_f32 %0, %1, %2" : "=v"(p3) : "v"(hi[2]), "v"(hi[3]));
            i32x4 pk = { p0, p1, p2, p3 };
            bf16x8 af = __builtin_bit_cast(bf16x8, pk);
            acc0 = __builtin_amdgcn_mfma_f32_16x16x32_bf16(af, B0[kk], acc0, 0, 0, 0);
            acc1 = __builtin_amdgcn_mfma_f32_16x16x32_bf16(af, B1[kk], acc1, 0, 0, 0);
        }

        float* ob = out + (long)t * 16 * 256 + (q * 4) * 256 + 2 * wave * 16 + r;
#pragma unroll
        for (int e = 0; e < 4; ++e) {
            ob[e * 256]      = acc0[e];
            ob[e * 256 + 16] = acc1[e];
        }
        asm volatile("s_waitcnt vmcnt(16)" ::: "memory");
        __builtin_amdgcn_s_barrier();
        __builtin_amdgcn_sched_barrier(0);
        slot = (slot == DEPTH - 1) ? 0 : slot + 1;
    }
}

extern "C" void kernel_launch(void* const* d_in, const int* in_sizes, int n_in,
                              void* d_out, int out_size, void* d_ws, size_t ws_size,
                              hipStream_t stream) {
    const int*   x     = (const int*)d_in[0];
    const float* core0 = (const float*)d_in[1];
    const float* core1 = (const float*)d_in[2];
    float* out = (float*)d_out;

    bf16x8* bpk   = (bf16x8*)d_ws;                         // 128 KB
    int*    hist  = (int*)((char*)d_ws + 131072);          // 13312 * 4 B
    int*    basec = (int*)((char*)d_ws + 184320);          // 13312 * 4 B
    int*    perm  = (int*)((char*)d_ws + 237568);          // 204800 * 4 B
    const size_t WS_NEED = 237568 + (size_t)NROWS * 4;     // ~1.06 MB

    pack_b_kernel<<<32, 256, 0, stream>>>(core1, bpk);
    if (ws_size >= WS_NEED) {
        zero_hist_kernel<<<13, 1024, 0, stream>>>(hist);
        hist_kernel<<<NROWS / 1024, 1024, 0, stream>>>(x, hist);
        scan_kernel<<<1, 1024, 0, stream>>>(hist, basec);
        scatter_kernel<<<NROWS / 1024, 1024, 0, stream>>>(x, basec, perm);
        tr_embed_sorted_kernel<<<GRID, 512, 0, stream>>>(x, core0, bpk, perm, out);
    } else {
        tr_embed_kernel<<<GRID, 512, 0, stream>>>(x, core0, bpk, out);
    }
}

// Round 19
// 107.889 us; speedup vs baseline: 1.3987x; 1.2186x over previous
//
#include <hip/hip_runtime.h>
#include <hip/hip_bf16.h>

#define VOCAB  200000
#define NTILES 12800            // 204800 rows / 16
#define GRID   512              // persistent blocks; grid caps residency at 2/CU
#define ITERS  25               // NTILES / GRID
#define DEPTH  3                // LDS A-buffer ring (2 tiles prefetch ahead)

typedef __attribute__((ext_vector_type(4))) float  f32x4;
typedef __attribute__((ext_vector_type(4))) int    i32x4;
typedef __attribute__((ext_vector_type(8))) __bf16 bf16x8;

typedef const __attribute__((address_space(1))) unsigned int* gas_u32p;
typedef __attribute__((address_space(3))) unsigned int* las_u32p;

__device__ __forceinline__ __bf16 f2bf(float f) {
    unsigned u = __builtin_bit_cast(unsigned, f);
    u += 0x7FFFu + ((u >> 16) & 1u);           // round-to-nearest-even
    unsigned short s = (unsigned short)(u >> 16);
    return __builtin_bit_cast(__bf16, s);
}

// Pack B into MFMA fragment order (verified round 1).
// k = a*16 + b;  B[k][j] = core1[b, j, a], core1 is (16,256,16).
// bpk[(kk*16 + nt)*64 + lane] : lane l elem e = B[kk*32 + (l>>4)*8 + e][nt*16 + (l&15)]
__global__ void pack_b_kernel(const float* __restrict__ core1, bf16x8* __restrict__ bpk) {
    int t    = blockIdx.x * 256 + threadIdx.x;   // 0..8191
    int lane = t & 63;
    int nt   = (t >> 6) & 15;
    int kk   = t >> 10;
    int j     = nt * 16 + (lane & 15);
    int kbase = kk * 32 + ((lane >> 4) * 8);
    bf16x8 v;
#pragma unroll
    for (int e = 0; e < 8; ++e) {
        int k = kbase + e;
        int b = k & 15, a = k >> 4;
        v[e] = f2bf(core1[(b * 256 + j) * 16 + a]);
    }
    bpk[t] = v;
}

// A-gather, FULL-LINE COALESCED remap. Inst (kk, h): lane l = q*16+r fetches
// chunk c = kk*8 + h*4 + q of row idx_r = core0[plane 2kk+h][idx_r][q*4..q*4+3]
// -> per row the 4 q-lanes read ONE contiguous 64 B line (one L2 transaction;
// the old map split every line across 2 insts x 2 pieces = 4 transactions).
// LDS image: abuf + kk*2048 + h*1024 + q*256 + r*16 (HW: base + lane*16).
__device__ __forceinline__ void issue_gather(const float* __restrict__ core0, int idx,
                                             int kk, char* abuf, int lane) {
    const int q = lane >> 4;
#pragma unroll
    for (int h = 0; h < 2; ++h) {
        const float* src = core0 + ((long)(2 * kk + h) * VOCAB + idx) * 16 + q * 4;
        __builtin_amdgcn_global_load_lds((gas_u32p)src,
                                         (las_u32p)(abuf + kk * 2048 + h * 1024), 16, 0, 0);
    }
}

// r9/r13/r15-proven skeleton: B panel in regs, 3-deep LDS A-ring filled by
// zero-VGPR global_load_lds, sIdx staged in LDS, direct C stores, counted
// vmcnt(16) + raw barrier per iter (ops newer than g(i+1) at the wait =
// st(i-1)[8] + g(i+2)[2] + st(i)[8] = 18 steady / 16 tail; r15-validated).
// A-fragment read (re-derived for the remap): lane (q,r), slab kk:
//   af[0..3] = chunk kk*8+2q  -> LDS kk*2048 + (q>>1)*1024 + ((2q)&3)*256 + r*16
//            = kk*2048 + q*512 + r*16;  af[4..7] at +256.  (checked q=0..3)
__global__ __launch_bounds__(512, 4) void tr_embed_kernel(
        const int* __restrict__ x, const float* __restrict__ core0,
        const bf16x8* __restrict__ bpk, float* __restrict__ out) {
    __shared__ char lds[DEPTH * 16384 + ITERS * 16 * 4];   // A-ring | idx
    char* const ldsA = lds;
    int*  const sIdx = (int*)(lds + DEPTH * 16384);
    const int tid  = threadIdx.x;
    const int lane = tid & 63;
    const int wave = tid >> 6;                  // 0..7
    const int r    = lane & 15;
    const int q    = lane >> 4;
    const int laneOff = q * 512 + r * 16;       // A-fragment LDS offset (remap)

    // B panel -> registers: wave w owns nt = 2w, 2w+1 (proven r9)
    bf16x8 B0[8], B1[8];
#pragma unroll
    for (int kk = 0; kk < 8; ++kk) {
        B0[kk] = bpk[(kk * 16 + 2 * wave)     * 64 + lane];
        B1[kk] = bpk[(kk * 16 + 2 * wave + 1) * 64 + lane];
    }

    const int b0 = blockIdx.x;

    // stage all idx values into LDS (off the vmcnt path; proven r9)
    for (int j = tid; j < ITERS * 16; j += 512)
        sIdx[j] = x[(b0 + (j >> 4) * GRID) * 16 + (j & 15)];
    __syncthreads();

    // prologue: gather tiles 0,1 into ring slots 0,1; full drain
#pragma unroll
    for (int p = 0; p < 2; ++p)
        issue_gather(core0, sIdx[p * 16 + r], wave, ldsA + p * 16384, lane);
    asm volatile("s_waitcnt vmcnt(0)" ::: "memory");
    __builtin_amdgcn_s_barrier();
    __builtin_amdgcn_sched_barrier(0);

    int slot = 0;
    for (int i = 0; i < ITERS; ++i) {
        const int t = b0 + i * GRID;
        char* cur = ldsA + slot * 16384;

        // issue gathers for tile i+2 into ring slot (slot+2)%3
        if (i + 2 < ITERS) {
            int ns = slot + 2; if (ns >= DEPTH) ns -= DEPTH;
            issue_gather(core0, sIdx[(i + 2) * 16 + r], wave, ldsA + ns * 16384, lane);
        }
        __builtin_amdgcn_sched_barrier(0);      // pin gather issue at iter top

        // ---- compute 16 rows x 32 cols per wave (LDS A + reg B) ----
        f32x4 acc0 = {}, acc1 = {};
#pragma unroll
        for (int kk = 0; kk < 8; ++kk) {
            f32x4 lo = *(const f32x4*)(cur + kk * 2048 + laneOff);
            f32x4 hi = *(const f32x4*)(cur + kk * 2048 + laneOff + 256);
            int p0, p1, p2, p3;                 // RNE packed f32->bf16
            asm("v_cvt_pk_bf16_f32 %0, %1, %2" : "=v"(p0) : "v"(lo[0]), "v"(lo[1]));
            asm("v_cvt_pk_bf16_f32 %0, %1, %2" : "=v"(p1) : "v"(lo[2]), "v"(lo[3]));
            asm("v_cvt_pk_bf16_f32 %0, %1, %2" : "=v"(p2) : "v"(hi[0]), "v"(hi[1]));
            asm("v_cvt_pk_bf16_f32 %0, %1, %2" : "=v"(p3) : "v"(hi[2]), "v"(hi[3]));
            i32x4 pk = { p0, p1, p2, p3 };
            bf16x8 af = __builtin_bit_cast(bf16x8, pk);
            acc0 = __builtin_amdgcn_mfma_f32_16x16x32_bf16(af, B0[kk], acc0, 0, 0, 0);
            acc1 = __builtin_amdgcn_mfma_f32_16x16x32_bf16(af, B1[kk], acc1, 0, 0, 0);
        }

        // ---- direct C stores (proven r9): col = lane&15, row = q*4 + e ----
        float* ob = out + (long)t * 16 * 256 + (q * 4) * 256 + 2 * wave * 16 + r;
#pragma unroll
        for (int e = 0; e < 4; ++e) {
            ob[e * 256]      = acc0[e];
            ob[e * 256 + 16] = acc1[e];
        }

        // counted drain (r15-validated math) + barrier
        asm volatile("s_waitcnt vmcnt(16)" ::: "memory");
        __builtin_amdgcn_s_barrier();
        __builtin_amdgcn_sched_barrier(0);

        slot = (slot == DEPTH - 1) ? 0 : slot + 1;
    }
}

extern "C" void kernel_launch(void* const* d_in, const int* in_sizes, int n_in,
                              void* d_out, int out_size, void* d_ws, size_t ws_size,
                              hipStream_t stream) {
    const int*   x     = (const int*)d_in[0];
    const float* core0 = (const float*)d_in[1];
    const float* core1 = (const float*)d_in[2];
    float* out = (float*)d_out;
    bf16x8* bpk = (bf16x8*)d_ws;                // 128 KB scratch

    pack_b_kernel<<<32, 256, 0, stream>>>(core1, bpk);
    tr_embed_kernel<<<GRID, 512, 0, stream>>>(x, core0, bpk, out);
}